// Round 5
// baseline (868.692 us; speedup 1.0000x reference)
//
#include <hip/hip_runtime.h>
#include <hip/hip_bf16.h>

#define B_ 2
#define S_ 2048
#define H_ 2048
#define NH_ 16
#define HD_ 128
#define M_ (B_*S_)   // 4096

typedef unsigned short u16;
typedef unsigned int u32;
typedef __attribute__((ext_vector_type(8))) short bhalf8_t;   // 8 bf16 in 4 VGPRs
typedef __attribute__((ext_vector_type(4))) float fx4_t;      // MFMA accumulator

__device__ __forceinline__ float bf2f(u16 v) {
    unsigned u = ((unsigned)v) << 16;
    return __builtin_bit_cast(float, u);
}
__device__ __forceinline__ u16 f2bf(float f) {
    unsigned u = __builtin_bit_cast(unsigned, f);
    unsigned r = u + 0x7fffu + ((u >> 16) & 1u);   // RNE
    return (u16)(r >> 16);
}
__device__ __forceinline__ void gload_lds16(const u16* g, u16* l) {
    __builtin_amdgcn_global_load_lds(
        (const __attribute__((address_space(1))) u32*)g,
        (__attribute__((address_space(3))) u32*)l, 16, 0, 0);
}

// ---------------- fp32 -> bf16 elementwise convert ---------------------------
__global__ __launch_bounds__(256) void cvt_bf16_k(const float* __restrict__ in,
                                                  u16* __restrict__ out) {
    int i = blockIdx.x * 256 + threadIdx.x;
    float4 v = ((const float4*)in)[i];
    ushort4 o;
    o.x = f2bf(v.x); o.y = f2bf(v.y); o.z = f2bf(v.z); o.w = f2bf(v.w);
    ((ushort4*)out)[i] = o;
}

// -------- weight transpose+convert: out_bf16[n][k] = in_f32[k][n], 2048x2048 --
__global__ __launch_bounds__(256) void transpose_cvt_k(const float* __restrict__ in,
                                                       u16* __restrict__ out) {
    __shared__ u16 tile[64][65];
    int k0 = blockIdx.y * 64, n0 = blockIdx.x * 64;
    int t = threadIdx.x;
    for (int i = 0; i < 16; i++) {
        int idx = t + i * 256;
        int r = idx >> 6, c = idx & 63;
        tile[r][c] = f2bf(in[(size_t)(k0 + r) * H_ + n0 + c]);
    }
    __syncthreads();
    for (int i = 0; i < 16; i++) {
        int idx = t + i * 256;
        int r = idx >> 6, c = idx & 63;
        out[(size_t)(n0 + r) * H_ + k0 + c] = tile[c][r];
    }
}

// ======== fused QKV GEMM: C = hs @ [Wq|Wk|Wv]^T, N = 6144 ====================
// 128x128 tile, BK=64, XOR-swizzled LDS, global_load_lds staging.
// Epilogue routes: n<2048 -> q [b,h,s,d]; <4096 -> k [b,h,s,d]; else V^T [b,h,d,s]
__global__ __launch_bounds__(256) void gemm_qkv(const u16* __restrict__ A,
                                                const u16* __restrict__ Bt,
                                                const float* __restrict__ bq,
                                                const float* __restrict__ bk,
                                                const float* __restrict__ bv,
                                                u16* __restrict__ qh,
                                                u16* __restrict__ kh,
                                                u16* __restrict__ vT) {
    const int Ksz = H_;
    __shared__ u16 As[128 * 64];
    __shared__ u16 Bs[128 * 64];
    int t = threadIdx.x;
    int wave = t >> 6, lane = t & 63;
    int lr = lane & 15, lq = lane >> 4;
    int m0 = blockIdx.y * 128, n0 = blockIdx.x * 128;
    int wm = (wave >> 1) * 64, wn = (wave & 1) * 64;

    fx4_t acc[4][4];
    for (int i = 0; i < 4; i++)
        for (int j = 0; j < 4; j++)
            acc[i][j] = (fx4_t){0.f, 0.f, 0.f, 0.f};

    for (int k0 = 0; k0 < Ksz; k0 += 64) {
        for (int i = 0; i < 4; i++) {
            int c = t + i * 256;
            int r = c >> 3, g = (c & 7) ^ (r & 7);
            gload_lds16(&A[(size_t)(m0 + r) * Ksz + k0 + g * 8], As + (size_t)c * 8);
            gload_lds16(&Bt[(size_t)(n0 + r) * Ksz + k0 + g * 8], Bs + (size_t)c * 8);
        }
        __syncthreads();
        for (int ds = 0; ds < 2; ds++) {
            bhalf8_t a[4], b[4];
            int cs = (ds * 4 + lq) ^ (lr & 7);
            for (int i = 0; i < 4; i++)
                a[i] = *(const bhalf8_t*)&As[(((wm + i * 16 + lr) << 3) + cs) * 8];
            for (int j = 0; j < 4; j++)
                b[j] = *(const bhalf8_t*)&Bs[(((wn + j * 16 + lr) << 3) + cs) * 8];
            for (int i = 0; i < 4; i++)
                for (int j = 0; j < 4; j++)
                    acc[i][j] = __builtin_amdgcn_mfma_f32_16x16x32_bf16(a[i], b[j], acc[i][j], 0, 0, 0);
        }
        __syncthreads();
    }
    int which = n0 >> 11;                       // 0=q 1=k 2=v (uniform per block)
    const float* bias = which == 0 ? bq : which == 1 ? bk : bv;
    for (int i = 0; i < 4; i++)
        for (int j = 0; j < 4; j++) {
            int row0 = m0 + wm + i * 16 + lq * 4;          // m = b*S + s
            int cc = (n0 & 2047) + wn + j * 16 + lr;       // c = h*HD + d
            float bvv = bias[cc];
            int bb = row0 >> 11, s = row0 & 2047;
            int hh = cc >> 7, d = cc & 127;
            if (which == 2) {
                ushort4 w;
                w.x = f2bf(acc[i][j][0] + bvv);
                w.y = f2bf(acc[i][j][1] + bvv);
                w.z = f2bf(acc[i][j][2] + bvv);
                w.w = f2bf(acc[i][j][3] + bvv);
                *(ushort4*)&vT[(((size_t)bb * NH_ + hh) * HD_ + d) * S_ + s] = w;
            } else {
                u16* dst = (which == 0 ? qh : kh);
                for (int r = 0; r < 4; r++)
                    dst[(((size_t)bb * NH_ + hh) * S_ + s + r) * HD_ + d] =
                        f2bf(acc[i][j][r] + bvv);
            }
        }
}

// ---------------- O-proj GEMM: out_f32[M][H] = attn @ WoT^T + bo -------------
__global__ __launch_bounds__(256) void gemm_out(const u16* __restrict__ A,
                                                const u16* __restrict__ Bt,
                                                const float* __restrict__ bias,
                                                float* __restrict__ C) {
    const int Ksz = H_, Nsz = H_;
    __shared__ u16 As[128 * 64];
    __shared__ u16 Bs[128 * 64];
    int t = threadIdx.x;
    int wave = t >> 6, lane = t & 63;
    int lr = lane & 15, lq = lane >> 4;
    int m0 = blockIdx.y * 128, n0 = blockIdx.x * 128;
    int wm = (wave >> 1) * 64, wn = (wave & 1) * 64;

    fx4_t acc[4][4];
    for (int i = 0; i < 4; i++)
        for (int j = 0; j < 4; j++)
            acc[i][j] = (fx4_t){0.f, 0.f, 0.f, 0.f};

    for (int k0 = 0; k0 < Ksz; k0 += 64) {
        for (int i = 0; i < 4; i++) {
            int c = t + i * 256;
            int r = c >> 3, g = (c & 7) ^ (r & 7);
            gload_lds16(&A[(size_t)(m0 + r) * Ksz + k0 + g * 8], As + (size_t)c * 8);
            gload_lds16(&Bt[(size_t)(n0 + r) * Ksz + k0 + g * 8], Bs + (size_t)c * 8);
        }
        __syncthreads();
        for (int ds = 0; ds < 2; ds++) {
            bhalf8_t a[4], b[4];
            int cs = (ds * 4 + lq) ^ (lr & 7);
            for (int i = 0; i < 4; i++)
                a[i] = *(const bhalf8_t*)&As[(((wm + i * 16 + lr) << 3) + cs) * 8];
            for (int j = 0; j < 4; j++)
                b[j] = *(const bhalf8_t*)&Bs[(((wn + j * 16 + lr) << 3) + cs) * 8];
            for (int i = 0; i < 4; i++)
                for (int j = 0; j < 4; j++)
                    acc[i][j] = __builtin_amdgcn_mfma_f32_16x16x32_bf16(a[i], b[j], acc[i][j], 0, 0, 0);
        }
        __syncthreads();
    }
    for (int i = 0; i < 4; i++)
        for (int j = 0; j < 4; j++) {
            int row0 = m0 + wm + i * 16 + lq * 4;
            int col = n0 + wn + j * 16 + lr;
            float bvv = bias[col];
            for (int r = 0; r < 4; r++)
                C[(size_t)(row0 + r) * Nsz + col] = acc[i][j][r] + bvv;
        }
}

// ---------------- RoPE in-place on q and k ([B,NH,S,HD], bf16) ---------------
__global__ __launch_bounds__(256) void rope_k(u16* __restrict__ q, u16* __restrict__ k) {
    int idx = blockIdx.x * 256 + threadIdx.x;   // B*NH*S*64 threads
    int i = idx & 63;
    int s = (idx >> 6) & 2047;
    int h = (idx >> 17) & 15;
    int b = idx >> 21;
    float inv = 1.0f / powf(10000.0f, (float)i * (1.0f / 64.0f));
    float ang = (float)s * inv;
    float sn, c;
    sincosf(ang, &sn, &c);
    size_t base = (((size_t)b * NH_ + h) * S_ + s) * HD_ + i;
    {
        float x1 = bf2f(q[base]), x2 = bf2f(q[base + 64]);
        q[base]      = f2bf(x1 * c - x2 * sn);
        q[base + 64] = f2bf(x2 * c + x1 * sn);
    }
    {
        float x1 = bf2f(k[base]), x2 = bf2f(k[base + 64]);
        k[base]      = f2bf(x1 * c - x2 * sn);
        k[base + 64] = f2bf(x2 * c + x1 * sn);
    }
}

// ---------------- flash attention, causal, barrier-free ----------------------
// K [b,h,s,d] and V^T [b,h,d,s] are read directly from global as B-fragments;
// LDS holds only the wave-private P transpose buffer. No __syncthreads in the
// k-loop -> waves run independently; occupancy VGPR-bound.
#define PROW 72
__global__ __launch_bounds__(256, 3) void flash_k(const u16* __restrict__ qh,
                                                  const u16* __restrict__ kh,
                                                  const u16* __restrict__ vT,
                                                  u16* __restrict__ attn) {
    __shared__ u16 Ps[4 * 16 * PROW];           // 9.2 KB, wave-private slices
    int t = threadIdx.x, wave = t >> 6, lane = t & 63;
    int lr = lane & 15, lq = lane >> 4;
    int q0 = (int)(gridDim.x - 1 - blockIdx.x) * 64;   // big causal tiles first
    int h = blockIdx.y, b = blockIdx.z;
    const float scale2 = 0.08838834764831845f * 1.44269504f;  // 1/sqrt(128)*log2e

    const u16* kbase = kh + ((size_t)b * NH_ + h) * S_ * HD_;
    const u16* vbase = vT + ((size_t)b * NH_ + h) * HD_ * S_;
    u16* Pw = Ps + wave * 16 * PROW;

    // Q fragments loaded once (A-layout): row = q0+wave*16+lr, k = ds*32+lq*8
    bhalf8_t aq[4];
    {
        const u16* qrow = qh + (((size_t)b * NH_ + h) * S_ + q0 + wave * 16 + lr) * HD_;
        for (int ds = 0; ds < 4; ds++)
            aq[ds] = *(const bhalf8_t*)&qrow[ds * 32 + lq * 8];
    }

    float m_i[4], l_i[4];
    fx4_t acc_o[8];
    for (int r = 0; r < 4; r++) { m_i[r] = -INFINITY; l_i[r] = 0.f; }
    for (int dt = 0; dt < 8; dt++) acc_o[dt] = (fx4_t){0.f, 0.f, 0.f, 0.f};

    bhalf8_t bones;
    for (int j = 0; j < 8; j++) bones[j] = (short)0x3F80;   // bf16 1.0

    int nkb = q0 / 64 + 1;
    for (int kbi = 0; kbi < nkb; kbi++) {
        int k0 = kbi * 64;

        // S = Q K^T : 16 rows x 64 cols; K B-frags direct from global
        fx4_t sacc[4];
        for (int nt = 0; nt < 4; nt++) sacc[nt] = (fx4_t){0.f, 0.f, 0.f, 0.f};
        for (int nt = 0; nt < 4; nt++) {
            const u16* krow = kbase + (size_t)(k0 + nt * 16 + lr) * HD_;
            for (int ds = 0; ds < 4; ds++) {
                bhalf8_t bk = *(const bhalf8_t*)&krow[ds * 32 + lq * 8];
                sacc[nt] = __builtin_amdgcn_mfma_f32_16x16x32_bf16(aq[ds], bk, sacc[nt], 0, 0, 0);
            }
        }

        // softmax in exp2 domain; lane holds rows lq*4+r, cols nt*16+lr
        float sv[4][4];
        for (int nt = 0; nt < 4; nt++)
            for (int r = 0; r < 4; r++)
                sv[nt][r] = sacc[nt][r] * scale2;
        if (kbi == nkb - 1) {                    // diagonal tile: apply causal mask
            for (int nt = 0; nt < 4; nt++)
                for (int r = 0; r < 4; r++) {
                    int kpos = k0 + nt * 16 + lr;
                    int qpos = q0 + wave * 16 + lq * 4 + r;
                    if (kpos > qpos) sv[nt][r] = -1e9f;
                }
        }
        float rmax[4], alpha[4];
        for (int r = 0; r < 4; r++)
            rmax[r] = fmaxf(fmaxf(sv[0][r], sv[1][r]), fmaxf(sv[2][r], sv[3][r]));
        for (int off = 1; off < 16; off <<= 1)
            for (int r = 0; r < 4; r++)
                rmax[r] = fmaxf(rmax[r], __shfl_xor(rmax[r], off, 64));
        for (int r = 0; r < 4; r++) {
            float mn = fmaxf(m_i[r], rmax[r]);
            alpha[r] = exp2f(m_i[r] - mn);
            m_i[r] = mn;
            for (int nt = 0; nt < 4; nt++)
                sv[nt][r] = exp2f(sv[nt][r] - mn);
            l_i[r] *= alpha[r];
        }
        for (int dt = 0; dt < 8; dt++)
            for (int r = 0; r < 4; r++) acc_o[dt][r] *= alpha[r];

        // P (C-layout) -> wave-private LDS -> A-layout
        for (int nt = 0; nt < 4; nt++)
            for (int r = 0; r < 4; r++)
                Pw[(lq * 4 + r) * PROW + nt * 16 + lr] = f2bf(sv[nt][r]);
        __asm__ volatile("s_waitcnt lgkmcnt(0)" ::: "memory");  // wave-local sync

        // O += P V ; V B-frags direct from global; row-sum via ones-MFMA
        fx4_t ls = (fx4_t){0.f, 0.f, 0.f, 0.f};
        for (int ds = 0; ds < 2; ds++) {
            bhalf8_t ap = *(const bhalf8_t*)&Pw[lr * PROW + ds * 32 + lq * 8];
            for (int dt = 0; dt < 8; dt++) {
                const u16* vrow = vbase + (size_t)(dt * 16 + lr) * S_;
                bhalf8_t bv = *(const bhalf8_t*)&vrow[k0 + ds * 32 + lq * 8];
                acc_o[dt] = __builtin_amdgcn_mfma_f32_16x16x32_bf16(ap, bv, acc_o[dt], 0, 0, 0);
            }
            ls = __builtin_amdgcn_mfma_f32_16x16x32_bf16(ap, bones, ls, 0, 0, 0);
        }
        for (int r = 0; r < 4; r++) l_i[r] += ls[r];
    }

    float rl[4];
    for (int r = 0; r < 4; r++) rl[r] = 1.f / l_i[r];
    for (int dt = 0; dt < 8; dt++)
        for (int r = 0; r < 4; r++) {
            size_t row = (size_t)(b * S_ + q0 + wave * 16 + lq * 4 + r);
            attn[(row * NH_ + h) * HD_ + dt * 16 + lr] = f2bf(acc_o[dt][r] * rl[r]);
        }
}

extern "C" void kernel_launch(void* const* d_in, const int* in_sizes, int n_in,
                              void* d_out, int out_size, void* d_ws, size_t ws_size,
                              hipStream_t stream) {
    const float* hs = (const float*)d_in[0];
    // d_in[1] = mask (causal triu) — hard-coded in flash_k
    const float* Wq = (const float*)d_in[2];
    const float* bq = (const float*)d_in[3];
    const float* Wk = (const float*)d_in[4];
    const float* bk = (const float*)d_in[5];
    const float* Wv = (const float*)d_in[6];
    const float* bv = (const float*)d_in[7];
    const float* Wo = (const float*)d_in[8];
    const float* bo = (const float*)d_in[9];
    float* out = (float*)d_out;

    u16* ws   = (u16*)d_ws;
    size_t WW = (size_t)H_ * H_;
    size_t AC = (size_t)M_ * H_;
    u16* hsb  = ws;
    u16* Wall = hsb + AC;        // [Wq^T | Wk^T | Wv^T] rows, 6144 x 2048
    u16* WoT  = Wall + 3 * WW;
    u16* qh   = WoT + WW;        // [b,h,s,d]
    u16* kh   = qh + AC;         // [b,h,s,d]
    u16* vT   = kh + AC;         // [b,h,d,s]
    u16* attn = vT + AC;         // [b,s,h,d]

    dim3 tb(256);

    cvt_bf16_k<<<dim3(AC / (256 * 4)), tb, 0, stream>>>(hs, hsb);

    dim3 gT(32, 32);
    transpose_cvt_k<<<gT, tb, 0, stream>>>(Wq, Wall);
    transpose_cvt_k<<<gT, tb, 0, stream>>>(Wk, Wall + WW);
    transpose_cvt_k<<<gT, tb, 0, stream>>>(Wv, Wall + 2 * WW);
    transpose_cvt_k<<<gT, tb, 0, stream>>>(Wo, WoT);

    gemm_qkv<<<dim3(3 * H_ / 128, M_ / 128), tb, 0, stream>>>(hsb, Wall, bq, bk, bv,
                                                              qh, kh, vT);

    rope_k<<<dim3((B_ * NH_ * S_ * 64) / 256), tb, 0, stream>>>(qh, kh);

    flash_k<<<dim3(S_ / 64, NH_, B_), tb, 0, stream>>>(qh, kh, vT, attn);

    gemm_out<<<dim3(H_ / 128, M_ / 128), tb, 0, stream>>>(attn, WoT, bo, out);
}

// Round 6
// 519.248 us; speedup vs baseline: 1.6730x; 1.6730x over previous
//
#include <hip/hip_runtime.h>
#include <hip/hip_bf16.h>

#define B_ 2
#define S_ 2048
#define H_ 2048
#define NH_ 16
#define HD_ 128
#define M_ (B_*S_)   // 4096

typedef unsigned short u16;
typedef unsigned int u32;
typedef __attribute__((ext_vector_type(8))) short bhalf8_t;   // 8 bf16 in 4 VGPRs
typedef __attribute__((ext_vector_type(4))) float fx4_t;      // MFMA accumulator

__device__ __forceinline__ float bf2f(u16 v) {
    unsigned u = ((unsigned)v) << 16;
    return __builtin_bit_cast(float, u);
}
__device__ __forceinline__ u16 f2bf(float f) {
    unsigned u = __builtin_bit_cast(unsigned, f);
    unsigned r = u + 0x7fffu + ((u >> 16) & 1u);   // RNE
    return (u16)(r >> 16);
}
__device__ __forceinline__ u16 f2bf_trunc(float f) {   // P in [0,1]; bias cancels in O/l
    return (u16)(__builtin_bit_cast(unsigned, f) >> 16);
}
__device__ __forceinline__ void gload_lds16(const u16* g, u16* l) {
    __builtin_amdgcn_global_load_lds(
        (const __attribute__((address_space(1))) u32*)g,
        (__attribute__((address_space(3))) u32*)l, 16, 0, 0);
}

// ---------------- fp32 -> bf16 elementwise convert ---------------------------
__global__ __launch_bounds__(256) void cvt_bf16_k(const float* __restrict__ in,
                                                  u16* __restrict__ out) {
    int i = blockIdx.x * 256 + threadIdx.x;
    float4 v = ((const float4*)in)[i];
    ushort4 o;
    o.x = f2bf(v.x); o.y = f2bf(v.y); o.z = f2bf(v.z); o.w = f2bf(v.w);
    ((ushort4*)out)[i] = o;
}

// -------- weight transpose+convert: out_bf16[n][k] = in_f32[k][n], 2048x2048 --
__global__ __launch_bounds__(256) void transpose_cvt_k(const float* __restrict__ in,
                                                       u16* __restrict__ out) {
    __shared__ u16 tile[64][65];
    int k0 = blockIdx.y * 64, n0 = blockIdx.x * 64;
    int t = threadIdx.x;
    for (int i = 0; i < 16; i++) {
        int idx = t + i * 256;
        int r = idx >> 6, c = idx & 63;
        tile[r][c] = f2bf(in[(size_t)(k0 + r) * H_ + n0 + c]);
    }
    __syncthreads();
    for (int i = 0; i < 16; i++) {
        int idx = t + i * 256;
        int r = idx >> 6, c = idx & 63;
        out[(size_t)(n0 + r) * H_ + k0 + c] = tile[c][r];
    }
}

// ======== fused QKV GEMM: C = hs @ [Wq|Wk|Wv]^T, N = 6144 ====================
__global__ __launch_bounds__(256) void gemm_qkv(const u16* __restrict__ A,
                                                const u16* __restrict__ Bt,
                                                const float* __restrict__ bq,
                                                const float* __restrict__ bk,
                                                const float* __restrict__ bv,
                                                u16* __restrict__ qh,
                                                u16* __restrict__ kh,
                                                u16* __restrict__ vT) {
    const int Ksz = H_;
    __shared__ u16 As[128 * 64];
    __shared__ u16 Bs[128 * 64];
    int t = threadIdx.x;
    int wave = t >> 6, lane = t & 63;
    int lr = lane & 15, lq = lane >> 4;
    int m0 = blockIdx.y * 128, n0 = blockIdx.x * 128;
    int wm = (wave >> 1) * 64, wn = (wave & 1) * 64;

    fx4_t acc[4][4];
    for (int i = 0; i < 4; i++)
        for (int j = 0; j < 4; j++)
            acc[i][j] = (fx4_t){0.f, 0.f, 0.f, 0.f};

    for (int k0 = 0; k0 < Ksz; k0 += 64) {
        for (int i = 0; i < 4; i++) {
            int c = t + i * 256;
            int r = c >> 3, g = (c & 7) ^ (r & 7);
            gload_lds16(&A[(size_t)(m0 + r) * Ksz + k0 + g * 8], As + (size_t)c * 8);
            gload_lds16(&Bt[(size_t)(n0 + r) * Ksz + k0 + g * 8], Bs + (size_t)c * 8);
        }
        __syncthreads();
        for (int ds = 0; ds < 2; ds++) {
            bhalf8_t a[4], b[4];
            int cs = (ds * 4 + lq) ^ (lr & 7);
            for (int i = 0; i < 4; i++)
                a[i] = *(const bhalf8_t*)&As[(((wm + i * 16 + lr) << 3) + cs) * 8];
            for (int j = 0; j < 4; j++)
                b[j] = *(const bhalf8_t*)&Bs[(((wn + j * 16 + lr) << 3) + cs) * 8];
            for (int i = 0; i < 4; i++)
                for (int j = 0; j < 4; j++)
                    acc[i][j] = __builtin_amdgcn_mfma_f32_16x16x32_bf16(a[i], b[j], acc[i][j], 0, 0, 0);
        }
        __syncthreads();
    }
    int which = n0 >> 11;                       // 0=q 1=k 2=v (uniform per block)
    const float* bias = which == 0 ? bq : which == 1 ? bk : bv;
    for (int i = 0; i < 4; i++)
        for (int j = 0; j < 4; j++) {
            int row0 = m0 + wm + i * 16 + lq * 4;          // m = b*S + s
            int cc = (n0 & 2047) + wn + j * 16 + lr;       // c = h*HD + d
            float bvv = bias[cc];
            int bb = row0 >> 11, s = row0 & 2047;
            int hh = cc >> 7, d = cc & 127;
            if (which == 2) {
                ushort4 w;
                w.x = f2bf(acc[i][j][0] + bvv);
                w.y = f2bf(acc[i][j][1] + bvv);
                w.z = f2bf(acc[i][j][2] + bvv);
                w.w = f2bf(acc[i][j][3] + bvv);
                *(ushort4*)&vT[(((size_t)bb * NH_ + hh) * HD_ + d) * S_ + s] = w;
            } else {
                u16* dst = (which == 0 ? qh : kh);
                for (int r = 0; r < 4; r++)
                    dst[(((size_t)bb * NH_ + hh) * S_ + s + r) * HD_ + d] =
                        f2bf(acc[i][j][r] + bvv);
            }
        }
}

// ---------------- O-proj GEMM: out_f32[M][H] = attn @ WoT^T + bo -------------
__global__ __launch_bounds__(256) void gemm_out(const u16* __restrict__ A,
                                                const u16* __restrict__ Bt,
                                                const float* __restrict__ bias,
                                                float* __restrict__ C) {
    const int Ksz = H_, Nsz = H_;
    __shared__ u16 As[128 * 64];
    __shared__ u16 Bs[128 * 64];
    int t = threadIdx.x;
    int wave = t >> 6, lane = t & 63;
    int lr = lane & 15, lq = lane >> 4;
    int m0 = blockIdx.y * 128, n0 = blockIdx.x * 128;
    int wm = (wave >> 1) * 64, wn = (wave & 1) * 64;

    fx4_t acc[4][4];
    for (int i = 0; i < 4; i++)
        for (int j = 0; j < 4; j++)
            acc[i][j] = (fx4_t){0.f, 0.f, 0.f, 0.f};

    for (int k0 = 0; k0 < Ksz; k0 += 64) {
        for (int i = 0; i < 4; i++) {
            int c = t + i * 256;
            int r = c >> 3, g = (c & 7) ^ (r & 7);
            gload_lds16(&A[(size_t)(m0 + r) * Ksz + k0 + g * 8], As + (size_t)c * 8);
            gload_lds16(&Bt[(size_t)(n0 + r) * Ksz + k0 + g * 8], Bs + (size_t)c * 8);
        }
        __syncthreads();
        for (int ds = 0; ds < 2; ds++) {
            bhalf8_t a[4], b[4];
            int cs = (ds * 4 + lq) ^ (lr & 7);
            for (int i = 0; i < 4; i++)
                a[i] = *(const bhalf8_t*)&As[(((wm + i * 16 + lr) << 3) + cs) * 8];
            for (int j = 0; j < 4; j++)
                b[j] = *(const bhalf8_t*)&Bs[(((wn + j * 16 + lr) << 3) + cs) * 8];
            for (int i = 0; i < 4; i++)
                for (int j = 0; j < 4; j++)
                    acc[i][j] = __builtin_amdgcn_mfma_f32_16x16x32_bf16(a[i], b[j], acc[i][j], 0, 0, 0);
        }
        __syncthreads();
    }
    for (int i = 0; i < 4; i++)
        for (int j = 0; j < 4; j++) {
            int row0 = m0 + wm + i * 16 + lq * 4;
            int col = n0 + wn + j * 16 + lr;
            float bvv = bias[col];
            for (int r = 0; r < 4; r++)
                C[(size_t)(row0 + r) * Nsz + col] = acc[i][j][r] + bvv;
        }
}

// ------- RoPE in-place on q and k ([B,NH,S,HD], bf16); q also pre-scaled -----
__global__ __launch_bounds__(256) void rope_k(u16* __restrict__ q, u16* __restrict__ k) {
    const float scale2 = 0.08838834764831845f * 1.44269504f;  // 1/sqrt(128)*log2e
    int idx = blockIdx.x * 256 + threadIdx.x;   // B*NH*S*64 threads
    int i = idx & 63;
    int s = (idx >> 6) & 2047;
    int h = (idx >> 17) & 15;
    int b = idx >> 21;
    float inv = 1.0f / powf(10000.0f, (float)i * (1.0f / 64.0f));
    float ang = (float)s * inv;
    float sn, c;
    sincosf(ang, &sn, &c);
    size_t base = (((size_t)b * NH_ + h) * S_ + s) * HD_ + i;
    {
        float x1 = bf2f(q[base]), x2 = bf2f(q[base + 64]);
        q[base]      = f2bf((x1 * c - x2 * sn) * scale2);
        q[base + 64] = f2bf((x2 * c + x1 * sn) * scale2);
    }
    {
        float x1 = bf2f(k[base]), x2 = bf2f(k[base + 64]);
        k[base]      = f2bf(x1 * c - x2 * sn);
        k[base + 64] = f2bf(x2 * c + x1 * sn);
    }
}

// ---------------- flash attention, causal, staged + pipelined ----------------
// block = (q-tile 64, head, batch); 4 waves x 16 q-rows. K double-buffered LDS,
// V single-buffered (staged at iter start, used post-softmax -> latency hidden,
// barrier #2 guarantees completion). Ps wave-private, two 32-col passes.
// LDS = 2*16K (K) + 16K (V) + 5K (Ps) = 53.0 KB -> 3 blocks/CU.
#define PROW2 40
__global__ __launch_bounds__(256, 3) void flash_k(const u16* __restrict__ qh,
                                                  const u16* __restrict__ kh,
                                                  const u16* __restrict__ vT,
                                                  u16* __restrict__ attn) {
    __shared__ u16 sm[2 * 8192 + 8192 + 4 * 16 * PROW2];
    u16* KsB = sm;              // [buf][64 rows][16 chunks of 8]
    u16* Vs  = sm + 16384;      // [128 d][8 chunks of 8]
    u16* Ps  = sm + 24576;      // [4 waves][16][PROW2]

    int t = threadIdx.x, wave = t >> 6, lane = t & 63;
    int lr = lane & 15, lq = lane >> 4;
    int q0 = (int)(gridDim.x - 1 - blockIdx.x) * 64;   // big causal tiles first
    int h = blockIdx.y, b = blockIdx.z;

    const u16* kbase = kh + ((size_t)b * NH_ + h) * S_ * HD_;
    const u16* vbase = vT + ((size_t)b * NH_ + h) * HD_ * S_;
    u16* Pw = Ps + wave * 16 * PROW2;

    // Q fragments direct from global (A-layout); q pre-scaled by 1/sqrt(d)*log2e
    bhalf8_t aq[4];
    {
        const u16* qrow = qh + (((size_t)b * NH_ + h) * S_ + q0 + wave * 16 + lr) * HD_;
        for (int ds = 0; ds < 4; ds++)
            aq[ds] = *(const bhalf8_t*)&qrow[ds * 32 + lq * 8];
    }

    float m_i[4], l_i[4];
    fx4_t acc_o[8];
    for (int r = 0; r < 4; r++) { m_i[r] = -INFINITY; l_i[r] = 0.f; }
    for (int dt = 0; dt < 8; dt++) acc_o[dt] = (fx4_t){0.f, 0.f, 0.f, 0.f};

    bhalf8_t bones;
    for (int j = 0; j < 8; j++) bones[j] = (short)0x3F80;   // bf16 1.0

    auto stageK = [&](int buf, int k0) {
        u16* dst = KsB + buf * 8192;
        for (int i = 0; i < 4; i++) {
            int c = t + i * 256;               // 64 rows x 16 chunks
            int r = c >> 4, g = (c & 15) ^ (r & 15);
            gload_lds16(&kbase[(size_t)(k0 + r) * HD_ + g * 8], dst + (size_t)c * 8);
        }
    };
    auto stageV = [&](int k0) {
        for (int i = 0; i < 4; i++) {
            int c = t + i * 256;               // 128 d-rows x 8 chunks
            int r = c >> 3, g = (c & 7) ^ (r & 7);
            gload_lds16(&vbase[(size_t)r * S_ + k0 + g * 8], Vs + (size_t)c * 8);
        }
    };

    int nkb = q0 / 64 + 1;
    stageK(0, 0);
    for (int kbi = 0; kbi < nkb; kbi++) {
        int cur = kbi & 1;
        int k0 = kbi * 64;
        __syncthreads();   // drains K(cur); all waves done with V/Ps of prev iter
        stageV(k0);
        if (kbi + 1 < nkb) stageK(cur ^ 1, k0 + 64);
        const u16* Kc = KsB + cur * 8192;

        // S = Q K^T : 16 rows x 64 cols (log2-domain, scale pre-folded into q)
        fx4_t sacc[4];
        for (int nt = 0; nt < 4; nt++) sacc[nt] = (fx4_t){0.f, 0.f, 0.f, 0.f};
        for (int nt = 0; nt < 4; nt++) {
            int r = nt * 16 + lr;
            for (int ds = 0; ds < 4; ds++) {
                bhalf8_t bk = *(const bhalf8_t*)&Kc[((r << 4) + ((ds * 4 + lq) ^ lr)) * 8];
                sacc[nt] = __builtin_amdgcn_mfma_f32_16x16x32_bf16(aq[ds], bk, sacc[nt], 0, 0, 0);
            }
        }

        // online softmax (exp2 domain); lane: rows lq*4+r, cols nt*16+lr
        float sv[4][4];
        for (int nt = 0; nt < 4; nt++)
            for (int r = 0; r < 4; r++)
                sv[nt][r] = sacc[nt][r];
        if (kbi == nkb - 1) {                    // diagonal tile only
            for (int nt = 0; nt < 4; nt++)
                for (int r = 0; r < 4; r++) {
                    int kpos = k0 + nt * 16 + lr;
                    int qpos = q0 + wave * 16 + lq * 4 + r;
                    if (kpos > qpos) sv[nt][r] = -1e30f;
                }
        }
        float rmax[4], alpha[4];
        for (int r = 0; r < 4; r++)
            rmax[r] = fmaxf(fmaxf(sv[0][r], sv[1][r]), fmaxf(sv[2][r], sv[3][r]));
        for (int off = 1; off < 16; off <<= 1)
            for (int r = 0; r < 4; r++)
                rmax[r] = fmaxf(rmax[r], __shfl_xor(rmax[r], off, 64));
        for (int r = 0; r < 4; r++) {
            float mn = fmaxf(m_i[r], rmax[r]);
            alpha[r] = exp2f(m_i[r] - mn);
            m_i[r] = mn;
            for (int nt = 0; nt < 4; nt++)
                sv[nt][r] = exp2f(sv[nt][r] - mn);
            l_i[r] *= alpha[r];
        }
        for (int dt = 0; dt < 8; dt++)
            for (int r = 0; r < 4; r++) acc_o[dt][r] *= alpha[r];

        __syncthreads();   // V loads (issued pre-QK by all waves) complete

        // PV in two 32-col passes through the half-width wave-private Ps
        fx4_t ls = (fx4_t){0.f, 0.f, 0.f, 0.f};
        for (int p = 0; p < 2; p++) {
            for (int nt2 = 0; nt2 < 2; nt2++)
                for (int r = 0; r < 4; r++)
                    Pw[(lq * 4 + r) * PROW2 + nt2 * 16 + lr] =
                        f2bf_trunc(sv[p * 2 + nt2][r]);
            __asm__ volatile("s_waitcnt lgkmcnt(0)" ::: "memory");  // wave-local
            bhalf8_t ap = *(const bhalf8_t*)&Pw[lr * PROW2 + lq * 8];
            for (int dt = 0; dt < 8; dt++) {
                int r = dt * 16 + lr;
                bhalf8_t bv = *(const bhalf8_t*)&Vs[((r << 3) + ((p * 4 + lq) ^ (lr & 7))) * 8];
                acc_o[dt] = __builtin_amdgcn_mfma_f32_16x16x32_bf16(ap, bv, acc_o[dt], 0, 0, 0);
            }
            ls = __builtin_amdgcn_mfma_f32_16x16x32_bf16(ap, bones, ls, 0, 0, 0);
        }
        for (int r = 0; r < 4; r++) l_i[r] += ls[r];
    }

    float rl[4];
    for (int r = 0; r < 4; r++) rl[r] = 1.f / l_i[r];
    for (int dt = 0; dt < 8; dt++)
        for (int r = 0; r < 4; r++) {
            size_t row = (size_t)(b * S_ + q0 + wave * 16 + lq * 4 + r);
            attn[(row * NH_ + h) * HD_ + dt * 16 + lr] = f2bf(acc_o[dt][r] * rl[r]);
        }
}

extern "C" void kernel_launch(void* const* d_in, const int* in_sizes, int n_in,
                              void* d_out, int out_size, void* d_ws, size_t ws_size,
                              hipStream_t stream) {
    const float* hs = (const float*)d_in[0];
    // d_in[1] = mask (causal triu) — hard-coded in flash_k
    const float* Wq = (const float*)d_in[2];
    const float* bq = (const float*)d_in[3];
    const float* Wk = (const float*)d_in[4];
    const float* bk = (const float*)d_in[5];
    const float* Wv = (const float*)d_in[6];
    const float* bv = (const float*)d_in[7];
    const float* Wo = (const float*)d_in[8];
    const float* bo = (const float*)d_in[9];
    float* out = (float*)d_out;

    u16* ws   = (u16*)d_ws;
    size_t WW = (size_t)H_ * H_;
    size_t AC = (size_t)M_ * H_;
    u16* hsb  = ws;
    u16* Wall = hsb + AC;        // [Wq^T | Wk^T | Wv^T] rows, 6144 x 2048
    u16* WoT  = Wall + 3 * WW;
    u16* qh   = WoT + WW;        // [b,h,s,d], pre-scaled
    u16* kh   = qh + AC;         // [b,h,s,d]
    u16* vT   = kh + AC;         // [b,h,d,s]
    u16* attn = vT + AC;         // [b,s,h,d]

    dim3 tb(256);

    cvt_bf16_k<<<dim3(AC / (256 * 4)), tb, 0, stream>>>(hs, hsb);

    dim3 gT(32, 32);
    transpose_cvt_k<<<gT, tb, 0, stream>>>(Wq, Wall);
    transpose_cvt_k<<<gT, tb, 0, stream>>>(Wk, Wall + WW);
    transpose_cvt_k<<<gT, tb, 0, stream>>>(Wv, Wall + 2 * WW);
    transpose_cvt_k<<<gT, tb, 0, stream>>>(Wo, WoT);

    gemm_qkv<<<dim3(3 * H_ / 128, M_ / 128), tb, 0, stream>>>(hsb, Wall, bq, bk, bv,
                                                              qh, kh, vT);

    rope_k<<<dim3((B_ * NH_ * S_ * 64) / 256), tb, 0, stream>>>(qh, kh);

    flash_k<<<dim3(S_ / 64, NH_, B_), tb, 0, stream>>>(qh, kh, vT, attn);

    gemm_out<<<dim3(H_ / 128, M_ / 128), tb, 0, stream>>>(attn, WoT, bo, out);
}